// Round 1
// baseline (2122.696 us; speedup 1.0000x reference)
//
#include <hip/hip_runtime.h>

#define N_NODES 50000
#define N_EDGES 600000
#define IN_F 16
#define HF 128
#define NC 4
#define NHL 19
#define HS_STRIDE 36  // 32 k-chunk + pad; *4B = 144 bytes, 16B-aligned rows

__device__ __forceinline__ float lrelu(float x) { return x > 0.f ? x : 0.01f * x; }

// ---------------- CSR build ----------------

__global__ void count_deg_k(const int* __restrict__ dst, int* __restrict__ cnt) {
    int e = blockIdx.x * 256 + threadIdx.x;
    if (e < N_EDGES) atomicAdd(&cnt[dst[e]], 1);
}

__global__ void deginv_k(const int* __restrict__ cnt, float* __restrict__ dinv) {
    int v = blockIdx.x * 256 + threadIdx.x;
    if (v < N_NODES) dinv[v] = 1.0f / fmaxf((float)cnt[v], 1.0f);
}

// single-block exclusive scan over 50000 counts -> rowptr[0..N_NODES]
__global__ void scan_k(const int* __restrict__ cnt, int* __restrict__ rowptr) {
    __shared__ int s[1024];
    __shared__ int carry;
    int t = threadIdx.x;
    if (t == 0) carry = 0;
    __syncthreads();
    for (int base = 0; base < N_NODES; base += 1024) {
        int v = (base + t < N_NODES) ? cnt[base + t] : 0;
        s[t] = v;
        __syncthreads();
        for (int off = 1; off < 1024; off <<= 1) {
            int x = (t >= off) ? s[t - off] : 0;
            __syncthreads();
            s[t] += x;
            __syncthreads();
        }
        int incl = s[t];
        int c0 = carry;
        if (base + t < N_NODES) rowptr[base + t] = c0 + incl - v;
        __syncthreads();
        if (t == 0) carry = c0 + s[1023];
        __syncthreads();
    }
    if (t == 0) rowptr[N_NODES] = carry;
}

__global__ void fill_k(const int* __restrict__ src, const int* __restrict__ dst,
                       const float* __restrict__ ea, const int* __restrict__ rowptr,
                       int* __restrict__ fill, int* __restrict__ csrc, float* __restrict__ cw) {
    int e = blockIdx.x * 256 + threadIdx.x;
    if (e < N_EDGES) {
        int d = dst[e];
        int pos = rowptr[d] + atomicAdd(&fill[d], 1);
        csrc[pos] = src[e];
        cw[pos]  = ea[e];
    }
}

// ---------------- input GEMM: T[50000x128] = X[50000x16] @ W[16x128] + b ----------------

__global__ void gemm_in_k(const float* __restrict__ X, const float* __restrict__ W,
                          const float* __restrict__ b, float* __restrict__ T) {
    __shared__ float Ws[IN_F * HF];  // 8 KB
    int t = threadIdx.x;
    ((float4*)Ws)[t]       = ((const float4*)W)[t];
    ((float4*)Ws)[t + 256] = ((const float4*)W)[t + 256];
    __syncthreads();
    int row = blockIdx.x * 16 + (t >> 4);
    if (row >= N_NODES) return;
    int tx = t & 15;
    int c0 = tx * 4, c1 = 64 + tx * 4;
    float4 a0 = *(const float4*)&b[c0];
    float4 a1 = *(const float4*)&b[c1];
    const float4* xr = (const float4*)(X + row * IN_F);
#pragma unroll
    for (int k4 = 0; k4 < 4; k4++) {
        float4 xv = xr[k4];
        const float* xp = (const float*)&xv;
#pragma unroll
        for (int kk = 0; kk < 4; kk++) {
            int k = k4 * 4 + kk;
            float4 w0 = *(const float4*)&Ws[k * HF + c0];
            float4 w1 = *(const float4*)&Ws[k * HF + c1];
            float xs = xp[kk];
            a0.x = fmaf(xs, w0.x, a0.x); a0.y = fmaf(xs, w0.y, a0.y);
            a0.z = fmaf(xs, w0.z, a0.z); a0.w = fmaf(xs, w0.w, a0.w);
            a1.x = fmaf(xs, w1.x, a1.x); a1.y = fmaf(xs, w1.y, a1.y);
            a1.z = fmaf(xs, w1.z, a1.z); a1.w = fmaf(xs, w1.w, a1.w);
        }
    }
    *(float4*)&T[row * HF + c0] = a0;
    *(float4*)&T[row * HF + c1] = a1;
}

// ---------------- hidden GEMM: T = H @ W + b, 128x128 tile, 8x8 per thread ----------------

__global__ __launch_bounds__(256) void gemm_h_k(const float* __restrict__ H,
                                                const float* __restrict__ W,
                                                const float* __restrict__ b,
                                                float* __restrict__ T) {
    __shared__ float Ws[32 * HF];          // 16 KB, k-major chunk
    __shared__ float Hs[128 * HS_STRIDE];  // 18 KB, natural [row][k] layout
    int t = threadIdx.x;
    int tx = t & 15, ty = t >> 4;
    int rbase = blockIdx.x * 128;
    int c0 = tx * 4, c1 = 64 + tx * 4;
    float4 b0 = *(const float4*)&b[c0];
    float4 b1 = *(const float4*)&b[c1];
    float acc[8][8];
#pragma unroll
    for (int i = 0; i < 8; i++) {
        acc[i][0] = b0.x; acc[i][1] = b0.y; acc[i][2] = b0.z; acc[i][3] = b0.w;
        acc[i][4] = b1.x; acc[i][5] = b1.y; acc[i][6] = b1.z; acc[i][7] = b1.w;
    }
    int srow = t >> 3;   // 0..31
    int sc4  = t & 7;    // 0..7 (float4 within 32-k chunk)

    for (int kc = 0; kc < HF; kc += 32) {
        const float4* Wg = (const float4*)(W + kc * HF);
#pragma unroll
        for (int i = 0; i < 4; i++)
            ((float4*)Ws)[t + i * 256] = Wg[t + i * 256];
#pragma unroll
        for (int i = 0; i < 4; i++) {
            int rl = srow + i * 32;
            int row = rbase + rl;
            if (row >= N_NODES) row = N_NODES - 1;  // clamp: stores are guarded later
            float4 v = *(const float4*)&H[row * HF + kc + sc4 * 4];
            *(float4*)&Hs[rl * HS_STRIDE + sc4 * 4] = v;
        }
        __syncthreads();
#pragma unroll
        for (int kq = 0; kq < 8; kq++) {
            float4 a[8];
#pragma unroll
            for (int i = 0; i < 8; i++)
                a[i] = *(const float4*)&Hs[(ty * 8 + i) * HS_STRIDE + kq * 4];
#pragma unroll
            for (int kk = 0; kk < 4; kk++) {
                int k = kq * 4 + kk;
                float4 w0 = *(const float4*)&Ws[k * HF + c0];
                float4 w1 = *(const float4*)&Ws[k * HF + c1];
                float wv[8] = {w0.x, w0.y, w0.z, w0.w, w1.x, w1.y, w1.z, w1.w};
#pragma unroll
                for (int i = 0; i < 8; i++) {
                    float av = ((const float*)&a[i])[kk];
#pragma unroll
                    for (int j = 0; j < 8; j++)
                        acc[i][j] = fmaf(av, wv[j], acc[i][j]);
                }
            }
        }
        __syncthreads();
    }
#pragma unroll
    for (int i = 0; i < 8; i++) {
        int row = rbase + ty * 8 + i;
        if (row < N_NODES) {
            *(float4*)&T[row * HF + c0] = make_float4(acc[i][0], acc[i][1], acc[i][2], acc[i][3]);
            *(float4*)&T[row * HF + c1] = make_float4(acc[i][4], acc[i][5], acc[i][6], acc[i][7]);
        }
    }
}

// ---------------- aggregation: O[v] = lrelu(deginv[v] * sum_e w_e * T[src_e]) ----------------

__global__ void agg_k(const float* __restrict__ T, float* __restrict__ O,
                      const int* __restrict__ rowptr, const int* __restrict__ csrc,
                      const float* __restrict__ cw, const float* __restrict__ dinv) {
    int v = blockIdx.x * 4 + (threadIdx.x >> 6);  // one wave per node
    if (v >= N_NODES) return;
    int lane = threadIdx.x & 63;
    int f = lane * 2;
    int e0 = rowptr[v], e1 = rowptr[v + 1];
    float ax = 0.f, ay = 0.f;
    for (int e = e0; e < e1; e++) {
        int s = csrc[e];
        float w = cw[e];
        float2 hv = *(const float2*)&T[s * HF + f];
        ax = fmaf(hv.x, w, ax);
        ay = fmaf(hv.y, w, ay);
    }
    float di = dinv[v];
    ax = lrelu(ax * di);
    ay = lrelu(ay * di);
    *(float2*)&O[v * HF + f] = make_float2(ax, ay);
}

// ---------------- output layer: out = H @ Wfc + bfc (N=4) ----------------

__global__ void fc_k(const float* __restrict__ H, const float* __restrict__ W,
                     const float* __restrict__ b, float* __restrict__ out) {
    int r = blockIdx.x * 256 + threadIdx.x;
    if (r >= N_NODES) return;
    float4 acc = *(const float4*)b;
    const float4* h4 = (const float4*)(H + r * HF);
    const float4* w4 = (const float4*)W;  // W[k][c], each row is one float4
#pragma unroll
    for (int k4 = 0; k4 < 32; k4++) {
        float4 hv = h4[k4];
        float4 wa = w4[k4 * 4 + 0], wb = w4[k4 * 4 + 1];
        float4 wc = w4[k4 * 4 + 2], wd = w4[k4 * 4 + 3];
        acc.x = fmaf(hv.x, wa.x, acc.x); acc.y = fmaf(hv.x, wa.y, acc.y);
        acc.z = fmaf(hv.x, wa.z, acc.z); acc.w = fmaf(hv.x, wa.w, acc.w);
        acc.x = fmaf(hv.y, wb.x, acc.x); acc.y = fmaf(hv.y, wb.y, acc.y);
        acc.z = fmaf(hv.y, wb.z, acc.z); acc.w = fmaf(hv.y, wb.w, acc.w);
        acc.x = fmaf(hv.z, wc.x, acc.x); acc.y = fmaf(hv.z, wc.y, acc.y);
        acc.z = fmaf(hv.z, wc.z, acc.z); acc.w = fmaf(hv.z, wc.w, acc.w);
        acc.x = fmaf(hv.w, wd.x, acc.x); acc.y = fmaf(hv.w, wd.y, acc.y);
        acc.z = fmaf(hv.w, wd.z, acc.z); acc.w = fmaf(hv.w, wd.w, acc.w);
    }
    *(float4*)&out[r * NC] = acc;
}

// ---------------- driver ----------------

extern "C" void kernel_launch(void* const* d_in, const int* in_sizes, int n_in,
                              void* d_out, int out_size, void* d_ws, size_t ws_size,
                              hipStream_t stream) {
    const float* X   = (const float*)d_in[0];
    const int*   EI  = (const int*)d_in[1];
    const float* EA  = (const float*)d_in[2];
    const float* Win = (const float*)d_in[3];
    const float* bin = (const float*)d_in[4];
    const float* Wh  = (const float*)d_in[5];
    const float* bh  = (const float*)d_in[6];
    const float* Wfc = (const float*)d_in[7];
    const float* bfc = (const float*)d_in[8];
    float* out = (float*)d_out;
    const int* src = EI;             // edge_index[0]
    const int* dst = EI + N_EDGES;   // edge_index[1]

    char* ws = (char*)d_ws;
    size_t off = 0;
    float* A    = (float*)(ws + off); off += (size_t)N_NODES * HF * 4;  // 25.6 MB
    float* B    = (float*)(ws + off); off += (size_t)N_NODES * HF * 4;  // 25.6 MB
    int* csrc   = (int*)(ws + off);   off += (size_t)N_EDGES * 4;
    float* cw   = (float*)(ws + off); off += (size_t)N_EDGES * 4;
    int* rowptr = (int*)(ws + off);   off += (((size_t)(N_NODES + 1) * 4 + 15) / 16) * 16;
    int* cnt    = (int*)(ws + off);   off += (size_t)N_NODES * 4;
    int* fill   = (int*)(ws + off);   off += (size_t)N_NODES * 4;
    float* dinv = (float*)(ws + off); off += (size_t)N_NODES * 4;

    hipMemsetAsync(cnt, 0, N_NODES * 4, stream);
    hipMemsetAsync(fill, 0, N_NODES * 4, stream);
    count_deg_k<<<(N_EDGES + 255) / 256, 256, 0, stream>>>(dst, cnt);
    deginv_k<<<(N_NODES + 255) / 256, 256, 0, stream>>>(cnt, dinv);
    scan_k<<<1, 1024, 0, stream>>>(cnt, rowptr);
    fill_k<<<(N_EDGES + 255) / 256, 256, 0, stream>>>(src, dst, EA, rowptr, fill, csrc, cw);

    gemm_in_k<<<(N_NODES + 15) / 16, 256, 0, stream>>>(X, Win, bin, B);
    agg_k<<<(N_NODES + 3) / 4, 256, 0, stream>>>(B, A, rowptr, csrc, cw, dinv);
    for (int l = 0; l < NHL; l++) {
        gemm_h_k<<<(N_NODES + 127) / 128, 256, 0, stream>>>(
            A, Wh + (size_t)l * HF * HF, bh + (size_t)l * HF, B);
        agg_k<<<(N_NODES + 3) / 4, 256, 0, stream>>>(B, A, rowptr, csrc, cw, dinv);
    }
    fc_k<<<(N_NODES + 255) / 256, 256, 0, stream>>>(A, Wfc, bfc, out);
}

// Round 2
// 1606.105 us; speedup vs baseline: 1.3216x; 1.3216x over previous
//
#include <hip/hip_runtime.h>

#define N_NODES 50000
#define N_EDGES 600000
#define IN_F 16
#define HF 128
#define NC 4
#define NHL 19
#define HS_STRIDE 36  // 32 k-chunk + pad; *4B = 144 bytes, 16B-aligned rows

__device__ __forceinline__ float lrelu(float x) { return x > 0.f ? x : 0.01f * x; }

// ---------------- CSR build ----------------

__global__ void count_deg_k(const int* __restrict__ dst, int* __restrict__ cnt) {
    int e = blockIdx.x * 256 + threadIdx.x;
    if (e < N_EDGES) atomicAdd(&cnt[dst[e]], 1);
}

__global__ void deginv_k(const int* __restrict__ cnt, float* __restrict__ dinv) {
    int v = blockIdx.x * 256 + threadIdx.x;
    if (v < N_NODES) dinv[v] = 1.0f / fmaxf((float)cnt[v], 1.0f);
}

// single-block exclusive scan via wave shuffles: 4 elements/thread, 4096/chunk
__global__ void scan_k(const int* __restrict__ cnt, int* __restrict__ rowptr) {
    __shared__ int wsum[16];
    __shared__ int carry_s;
    int t = threadIdx.x;
    int lane = t & 63, wid = t >> 6;
    if (t == 0) carry_s = 0;
    __syncthreads();
    for (int base = 0; base < N_NODES; base += 4096) {
        int idx = base + t * 4;
        int4 v = make_int4(0, 0, 0, 0);
        if (idx + 3 < N_NODES) v = *(const int4*)&cnt[idx];
        else {
            if (idx     < N_NODES) v.x = cnt[idx];
            if (idx + 1 < N_NODES) v.y = cnt[idx + 1];
            if (idx + 2 < N_NODES) v.z = cnt[idx + 2];
            if (idx + 3 < N_NODES) v.w = cnt[idx + 3];
        }
        int s1 = v.x + v.y, s2 = s1 + v.z, total = s2 + v.w;
        // inclusive wave scan of per-thread totals
        int sc = total;
#pragma unroll
        for (int off = 1; off < 64; off <<= 1) {
            int u = __shfl_up(sc, off, 64);
            if (lane >= off) sc += u;
        }
        if (lane == 63) wsum[wid] = sc;
        __syncthreads();
        if (t < 16) {
            int w = wsum[t];
#pragma unroll
            for (int off = 1; off < 16; off <<= 1) {
                int u = __shfl_up(w, off, 64);
                if (t >= off) w += u;
            }
            wsum[t] = w;  // inclusive scan of wave totals
        }
        __syncthreads();
        int prefix = carry_s + (wid > 0 ? wsum[wid - 1] : 0) + (sc - total);
        if (idx     < N_NODES) rowptr[idx]     = prefix;
        if (idx + 1 < N_NODES) rowptr[idx + 1] = prefix + v.x;
        if (idx + 2 < N_NODES) rowptr[idx + 2] = prefix + s1;
        if (idx + 3 < N_NODES) rowptr[idx + 3] = prefix + s2;
        __syncthreads();
        if (t == 0) carry_s += wsum[15];
        __syncthreads();
    }
    if (t == 0) rowptr[N_NODES] = carry_s;
}

// fill CSR; fold dinv[dst] into the edge weight so agg is a pure weighted sum
__global__ void fill_k(const int* __restrict__ src, const int* __restrict__ dst,
                       const float* __restrict__ ea, const int* __restrict__ rowptr,
                       int* __restrict__ fill, int* __restrict__ csrc, float* __restrict__ cw,
                       const float* __restrict__ dinv) {
    int e = blockIdx.x * 256 + threadIdx.x;
    if (e < N_EDGES) {
        int d = dst[e];
        int pos = rowptr[d] + atomicAdd(&fill[d], 1);
        csrc[pos] = src[e];
        cw[pos]   = ea[e] * dinv[d];
    }
}

// ---------------- input GEMM: T[50000x128] = X[50000x16] @ W[16x128] + b ----------------

__global__ void gemm_in_k(const float* __restrict__ X, const float* __restrict__ W,
                          const float* __restrict__ b, float* __restrict__ T) {
    __shared__ float Ws[IN_F * HF];  // 8 KB
    int t = threadIdx.x;
    ((float4*)Ws)[t]       = ((const float4*)W)[t];
    ((float4*)Ws)[t + 256] = ((const float4*)W)[t + 256];
    __syncthreads();
    int row = blockIdx.x * 16 + (t >> 4);
    if (row >= N_NODES) return;
    int tx = t & 15;
    int c0 = tx * 4, c1 = 64 + tx * 4;
    float4 a0 = *(const float4*)&b[c0];
    float4 a1 = *(const float4*)&b[c1];
    const float4* xr = (const float4*)(X + row * IN_F);
#pragma unroll
    for (int k4 = 0; k4 < 4; k4++) {
        float4 xv = xr[k4];
        const float* xp = (const float*)&xv;
#pragma unroll
        for (int kk = 0; kk < 4; kk++) {
            int k = k4 * 4 + kk;
            float4 w0 = *(const float4*)&Ws[k * HF + c0];
            float4 w1 = *(const float4*)&Ws[k * HF + c1];
            float xs = xp[kk];
            a0.x = fmaf(xs, w0.x, a0.x); a0.y = fmaf(xs, w0.y, a0.y);
            a0.z = fmaf(xs, w0.z, a0.z); a0.w = fmaf(xs, w0.w, a0.w);
            a1.x = fmaf(xs, w1.x, a1.x); a1.y = fmaf(xs, w1.y, a1.y);
            a1.z = fmaf(xs, w1.z, a1.z); a1.w = fmaf(xs, w1.w, a1.w);
        }
    }
    *(float4*)&T[row * HF + c0] = a0;
    *(float4*)&T[row * HF + c1] = a1;
}

// ---------------- hidden GEMM: T = H @ W + b, 128x128 tile, 8x8 per thread ----------------

__global__ __launch_bounds__(256) void gemm_h_k(const float* __restrict__ H,
                                                const float* __restrict__ W,
                                                const float* __restrict__ b,
                                                float* __restrict__ T) {
    __shared__ float Ws[32 * HF];          // 16 KB, k-major chunk
    __shared__ float Hs[128 * HS_STRIDE];  // 18 KB, natural [row][k] layout
    int t = threadIdx.x;
    int tx = t & 15, ty = t >> 4;
    int rbase = blockIdx.x * 128;
    int c0 = tx * 4, c1 = 64 + tx * 4;
    float4 b0 = *(const float4*)&b[c0];
    float4 b1 = *(const float4*)&b[c1];
    float acc[8][8];
#pragma unroll
    for (int i = 0; i < 8; i++) {
        acc[i][0] = b0.x; acc[i][1] = b0.y; acc[i][2] = b0.z; acc[i][3] = b0.w;
        acc[i][4] = b1.x; acc[i][5] = b1.y; acc[i][6] = b1.z; acc[i][7] = b1.w;
    }
    int srow = t >> 3;   // 0..31
    int sc4  = t & 7;    // 0..7 (float4 within 32-k chunk)

    for (int kc = 0; kc < HF; kc += 32) {
        const float4* Wg = (const float4*)(W + kc * HF);
#pragma unroll
        for (int i = 0; i < 4; i++)
            ((float4*)Ws)[t + i * 256] = Wg[t + i * 256];
#pragma unroll
        for (int i = 0; i < 4; i++) {
            int rl = srow + i * 32;
            int row = rbase + rl;
            if (row >= N_NODES) row = N_NODES - 1;  // clamp: stores are guarded later
            float4 v = *(const float4*)&H[row * HF + kc + sc4 * 4];
            *(float4*)&Hs[rl * HS_STRIDE + sc4 * 4] = v;
        }
        __syncthreads();
#pragma unroll
        for (int kq = 0; kq < 8; kq++) {
            float4 a[8];
#pragma unroll
            for (int i = 0; i < 8; i++)
                a[i] = *(const float4*)&Hs[(ty * 8 + i) * HS_STRIDE + kq * 4];
#pragma unroll
            for (int kk = 0; kk < 4; kk++) {
                int k = kq * 4 + kk;
                float4 w0 = *(const float4*)&Ws[k * HF + c0];
                float4 w1 = *(const float4*)&Ws[k * HF + c1];
                float wv[8] = {w0.x, w0.y, w0.z, w0.w, w1.x, w1.y, w1.z, w1.w};
#pragma unroll
                for (int i = 0; i < 8; i++) {
                    float av = ((const float*)&a[i])[kk];
#pragma unroll
                    for (int j = 0; j < 8; j++)
                        acc[i][j] = fmaf(av, wv[j], acc[i][j]);
                }
            }
        }
        __syncthreads();
    }
#pragma unroll
    for (int i = 0; i < 8; i++) {
        int row = rbase + ty * 8 + i;
        if (row < N_NODES) {
            *(float4*)&T[row * HF + c0] = make_float4(acc[i][0], acc[i][1], acc[i][2], acc[i][3]);
            *(float4*)&T[row * HF + c1] = make_float4(acc[i][4], acc[i][5], acc[i][6], acc[i][7]);
        }
    }
}

// ---------------- aggregation: O[v] = lrelu(sum_e cw_e * T[src_e]) ----------------
// 2 waves per node (64 feats each), wave-uniform scalar (csrc,cw) loads, 4x unroll.

__global__ __launch_bounds__(256) void agg_k(const float* __restrict__ T, float* __restrict__ O,
                                             const int* __restrict__ rowptr,
                                             const int* __restrict__ csrc,
                                             const float* __restrict__ cw) {
    int gw = blockIdx.x * 4 + (threadIdx.x >> 6);  // global wave id
    int v = gw >> 1;
    if (v >= N_NODES) return;
    int half = gw & 1;
    int lane = threadIdx.x & 63;
    int f = half * 64 + lane;
    int e0 = __builtin_amdgcn_readfirstlane(rowptr[v]);
    int e1 = __builtin_amdgcn_readfirstlane(rowptr[v + 1]);
    float acc = 0.f;
    int e = e0;
    for (; e + 4 <= e1; e += 4) {
        int   s0 = csrc[e],   s1 = csrc[e + 1], s2 = csrc[e + 2], s3 = csrc[e + 3];
        float w0 = cw[e],     w1 = cw[e + 1],   w2 = cw[e + 2],   w3 = cw[e + 3];
        float t0 = T[(size_t)s0 * HF + f];
        float t1 = T[(size_t)s1 * HF + f];
        float t2 = T[(size_t)s2 * HF + f];
        float t3 = T[(size_t)s3 * HF + f];
        acc = fmaf(t0, w0, acc);
        acc = fmaf(t1, w1, acc);
        acc = fmaf(t2, w2, acc);
        acc = fmaf(t3, w3, acc);
    }
    for (; e < e1; e++)
        acc = fmaf(T[(size_t)csrc[e] * HF + f], cw[e], acc);
    O[(size_t)v * HF + f] = lrelu(acc);
}

// ---------------- output layer: out = H @ Wfc + bfc (N=4) ----------------

__global__ void fc_k(const float* __restrict__ H, const float* __restrict__ W,
                     const float* __restrict__ b, float* __restrict__ out) {
    int r = blockIdx.x * 256 + threadIdx.x;
    if (r >= N_NODES) return;
    float4 acc = *(const float4*)b;
    const float4* h4 = (const float4*)(H + r * HF);
    const float4* w4 = (const float4*)W;  // W[k][c], each row is one float4
#pragma unroll
    for (int k4 = 0; k4 < 32; k4++) {
        float4 hv = h4[k4];
        float4 wa = w4[k4 * 4 + 0], wb = w4[k4 * 4 + 1];
        float4 wc = w4[k4 * 4 + 2], wd = w4[k4 * 4 + 3];
        acc.x = fmaf(hv.x, wa.x, acc.x); acc.y = fmaf(hv.x, wa.y, acc.y);
        acc.z = fmaf(hv.x, wa.z, acc.z); acc.w = fmaf(hv.x, wa.w, acc.w);
        acc.x = fmaf(hv.y, wb.x, acc.x); acc.y = fmaf(hv.y, wb.y, acc.y);
        acc.z = fmaf(hv.y, wb.z, acc.z); acc.w = fmaf(hv.y, wb.w, acc.w);
        acc.x = fmaf(hv.z, wc.x, acc.x); acc.y = fmaf(hv.z, wc.y, acc.y);
        acc.z = fmaf(hv.z, wc.z, acc.z); acc.w = fmaf(hv.z, wc.w, acc.w);
        acc.x = fmaf(hv.w, wd.x, acc.x); acc.y = fmaf(hv.w, wd.y, acc.y);
        acc.z = fmaf(hv.w, wd.z, acc.z); acc.w = fmaf(hv.w, wd.w, acc.w);
    }
    *(float4*)&out[r * NC] = acc;
}

// ---------------- driver ----------------

extern "C" void kernel_launch(void* const* d_in, const int* in_sizes, int n_in,
                              void* d_out, int out_size, void* d_ws, size_t ws_size,
                              hipStream_t stream) {
    const float* X   = (const float*)d_in[0];
    const int*   EI  = (const int*)d_in[1];
    const float* EA  = (const float*)d_in[2];
    const float* Win = (const float*)d_in[3];
    const float* bin = (const float*)d_in[4];
    const float* Wh  = (const float*)d_in[5];
    const float* bh  = (const float*)d_in[6];
    const float* Wfc = (const float*)d_in[7];
    const float* bfc = (const float*)d_in[8];
    float* out = (float*)d_out;
    const int* src = EI;             // edge_index[0]
    const int* dst = EI + N_EDGES;   // edge_index[1]

    char* ws = (char*)d_ws;
    size_t off = 0;
    float* A    = (float*)(ws + off); off += (size_t)N_NODES * HF * 4;  // 25.6 MB
    float* B    = (float*)(ws + off); off += (size_t)N_NODES * HF * 4;  // 25.6 MB
    int* csrc   = (int*)(ws + off);   off += (size_t)N_EDGES * 4;
    float* cw   = (float*)(ws + off); off += (size_t)N_EDGES * 4;
    int* rowptr = (int*)(ws + off);   off += (((size_t)(N_NODES + 1) * 4 + 15) / 16) * 16;
    int* cnt    = (int*)(ws + off);   off += (size_t)N_NODES * 4;
    int* fill   = (int*)(ws + off);   off += (size_t)N_NODES * 4;
    float* dinv = (float*)(ws + off); off += (size_t)N_NODES * 4;

    hipMemsetAsync(cnt, 0, N_NODES * 4, stream);
    hipMemsetAsync(fill, 0, N_NODES * 4, stream);
    count_deg_k<<<(N_EDGES + 255) / 256, 256, 0, stream>>>(dst, cnt);
    deginv_k<<<(N_NODES + 255) / 256, 256, 0, stream>>>(cnt, dinv);
    scan_k<<<1, 1024, 0, stream>>>(cnt, rowptr);
    fill_k<<<(N_EDGES + 255) / 256, 256, 0, stream>>>(src, dst, EA, rowptr, fill, csrc, cw, dinv);

    gemm_in_k<<<(N_NODES + 15) / 16, 256, 0, stream>>>(X, Win, bin, B);
    agg_k<<<(2 * N_NODES + 3) / 4, 256, 0, stream>>>(B, A, rowptr, csrc, cw);
    for (int l = 0; l < NHL; l++) {
        gemm_h_k<<<(N_NODES + 127) / 128, 256, 0, stream>>>(
            A, Wh + (size_t)l * HF * HF, bh + (size_t)l * HF, B);
        agg_k<<<(2 * N_NODES + 3) / 4, 256, 0, stream>>>(B, A, rowptr, csrc, cw);
    }
    fc_k<<<(N_NODES + 255) / 256, 256, 0, stream>>>(A, Wfc, bfc, out);
}

// Round 3
// 1543.296 us; speedup vs baseline: 1.3754x; 1.0407x over previous
//
#include <hip/hip_runtime.h>

#define N_NODES 50000
#define N_EDGES 600000
#define IN_F 16
#define HF 128
#define NC 4
#define NHL 19
#define HS_STRIDE 36  // 32 k-chunk + pad; *4B = 144 bytes, 16B-aligned rows

__device__ __forceinline__ float lrelu(float x) { return x > 0.f ? x : 0.01f * x; }

// ---------------- CSR build ----------------

__global__ void count_deg_k(const int* __restrict__ dst, int* __restrict__ cnt) {
    int e = blockIdx.x * 256 + threadIdx.x;
    if (e < N_EDGES) atomicAdd(&cnt[dst[e]], 1);
}

__global__ void deginv_k(const int* __restrict__ cnt, float* __restrict__ dinv) {
    int v = blockIdx.x * 256 + threadIdx.x;
    if (v < N_NODES) dinv[v] = 1.0f / fmaxf((float)cnt[v], 1.0f);
}

// single-block exclusive scan via wave shuffles: 4 elements/thread, 4096/chunk
__global__ void scan_k(const int* __restrict__ cnt, int* __restrict__ rowptr) {
    __shared__ int wsum[16];
    __shared__ int carry_s;
    int t = threadIdx.x;
    int lane = t & 63, wid = t >> 6;
    if (t == 0) carry_s = 0;
    __syncthreads();
    for (int base = 0; base < N_NODES; base += 4096) {
        int idx = base + t * 4;
        int4 v = make_int4(0, 0, 0, 0);
        if (idx + 3 < N_NODES) v = *(const int4*)&cnt[idx];
        else {
            if (idx     < N_NODES) v.x = cnt[idx];
            if (idx + 1 < N_NODES) v.y = cnt[idx + 1];
            if (idx + 2 < N_NODES) v.z = cnt[idx + 2];
            if (idx + 3 < N_NODES) v.w = cnt[idx + 3];
        }
        int s1 = v.x + v.y, s2 = s1 + v.z, total = s2 + v.w;
        int sc = total;
#pragma unroll
        for (int off = 1; off < 64; off <<= 1) {
            int u = __shfl_up(sc, off, 64);
            if (lane >= off) sc += u;
        }
        if (lane == 63) wsum[wid] = sc;
        __syncthreads();
        if (t < 16) {
            int w = wsum[t];
#pragma unroll
            for (int off = 1; off < 16; off <<= 1) {
                int u = __shfl_up(w, off, 64);
                if (t >= off) w += u;
            }
            wsum[t] = w;
        }
        __syncthreads();
        int prefix = carry_s + (wid > 0 ? wsum[wid - 1] : 0) + (sc - total);
        if (idx     < N_NODES) rowptr[idx]     = prefix;
        if (idx + 1 < N_NODES) rowptr[idx + 1] = prefix + v.x;
        if (idx + 2 < N_NODES) rowptr[idx + 2] = prefix + s1;
        if (idx + 3 < N_NODES) rowptr[idx + 3] = prefix + s2;
        __syncthreads();
        if (t == 0) carry_s += wsum[15];
        __syncthreads();
    }
    if (t == 0) rowptr[N_NODES] = carry_s;
}

// fill CSR: one int2 {src, bitcast(ea*dinv[dst])} store per edge
__global__ void fill_k(const int* __restrict__ src, const int* __restrict__ dst,
                       const float* __restrict__ ea, const int* __restrict__ rowptr,
                       int* __restrict__ fill, int2* __restrict__ edg,
                       const float* __restrict__ dinv) {
    int e = blockIdx.x * 256 + threadIdx.x;
    if (e < N_EDGES) {
        int d = dst[e];
        int pos = rowptr[d] + atomicAdd(&fill[d], 1);
        edg[pos] = make_int2(src[e], __float_as_int(ea[e] * dinv[d]));
    }
}

// ---------------- input GEMM: T[50000x128] = X[50000x16] @ W[16x128] + b ----------------

__global__ void gemm_in_k(const float* __restrict__ X, const float* __restrict__ W,
                          const float* __restrict__ b, float* __restrict__ T) {
    __shared__ float Ws[IN_F * HF];  // 8 KB
    int t = threadIdx.x;
    ((float4*)Ws)[t]       = ((const float4*)W)[t];
    ((float4*)Ws)[t + 256] = ((const float4*)W)[t + 256];
    __syncthreads();
    int row = blockIdx.x * 16 + (t >> 4);
    if (row >= N_NODES) return;
    int tx = t & 15;
    int c0 = tx * 4, c1 = 64 + tx * 4;
    float4 a0 = *(const float4*)&b[c0];
    float4 a1 = *(const float4*)&b[c1];
    const float4* xr = (const float4*)(X + row * IN_F);
#pragma unroll
    for (int k4 = 0; k4 < 4; k4++) {
        float4 xv = xr[k4];
        const float* xp = (const float*)&xv;
#pragma unroll
        for (int kk = 0; kk < 4; kk++) {
            int k = k4 * 4 + kk;
            float4 w0 = *(const float4*)&Ws[k * HF + c0];
            float4 w1 = *(const float4*)&Ws[k * HF + c1];
            float xs = xp[kk];
            a0.x = fmaf(xs, w0.x, a0.x); a0.y = fmaf(xs, w0.y, a0.y);
            a0.z = fmaf(xs, w0.z, a0.z); a0.w = fmaf(xs, w0.w, a0.w);
            a1.x = fmaf(xs, w1.x, a1.x); a1.y = fmaf(xs, w1.y, a1.y);
            a1.z = fmaf(xs, w1.z, a1.z); a1.w = fmaf(xs, w1.w, a1.w);
        }
    }
    *(float4*)&T[row * HF + c0] = a0;
    *(float4*)&T[row * HF + c1] = a1;
}

// ---------------- hidden GEMM: T = H @ W + b, 128x128 tile, 8x8 per thread ----------------

__global__ __launch_bounds__(256) void gemm_h_k(const float* __restrict__ H,
                                                const float* __restrict__ W,
                                                const float* __restrict__ b,
                                                float* __restrict__ T) {
    __shared__ float Ws[32 * HF];          // 16 KB, k-major chunk
    __shared__ float Hs[128 * HS_STRIDE];  // 18 KB
    int t = threadIdx.x;
    int tx = t & 15, ty = t >> 4;
    int rbase = blockIdx.x * 128;
    int c0 = tx * 4, c1 = 64 + tx * 4;
    float4 b0 = *(const float4*)&b[c0];
    float4 b1 = *(const float4*)&b[c1];
    float acc[8][8];
#pragma unroll
    for (int i = 0; i < 8; i++) {
        acc[i][0] = b0.x; acc[i][1] = b0.y; acc[i][2] = b0.z; acc[i][3] = b0.w;
        acc[i][4] = b1.x; acc[i][5] = b1.y; acc[i][6] = b1.z; acc[i][7] = b1.w;
    }
    int srow = t >> 3;   // 0..31
    int sc4  = t & 7;    // 0..7

    for (int kc = 0; kc < HF; kc += 32) {
        const float4* Wg = (const float4*)(W + kc * HF);
#pragma unroll
        for (int i = 0; i < 4; i++)
            ((float4*)Ws)[t + i * 256] = Wg[t + i * 256];
#pragma unroll
        for (int i = 0; i < 4; i++) {
            int rl = srow + i * 32;
            int row = rbase + rl;
            if (row >= N_NODES) row = N_NODES - 1;
            float4 v = *(const float4*)&H[row * HF + kc + sc4 * 4];
            *(float4*)&Hs[rl * HS_STRIDE + sc4 * 4] = v;
        }
        __syncthreads();
#pragma unroll
        for (int kq = 0; kq < 8; kq++) {
            float4 a[8];
#pragma unroll
            for (int i = 0; i < 8; i++)
                a[i] = *(const float4*)&Hs[(ty * 8 + i) * HS_STRIDE + kq * 4];
#pragma unroll
            for (int kk = 0; kk < 4; kk++) {
                int k = kq * 4 + kk;
                float4 w0 = *(const float4*)&Ws[k * HF + c0];
                float4 w1 = *(const float4*)&Ws[k * HF + c1];
                float wv[8] = {w0.x, w0.y, w0.z, w0.w, w1.x, w1.y, w1.z, w1.w};
#pragma unroll
                for (int i = 0; i < 8; i++) {
                    float av = ((const float*)&a[i])[kk];
#pragma unroll
                    for (int j = 0; j < 8; j++)
                        acc[i][j] = fmaf(av, wv[j], acc[i][j]);
                }
            }
        }
        __syncthreads();
    }
#pragma unroll
    for (int i = 0; i < 8; i++) {
        int row = rbase + ty * 8 + i;
        if (row < N_NODES) {
            *(float4*)&T[row * HF + c0] = make_float4(acc[i][0], acc[i][1], acc[i][2], acc[i][3]);
            *(float4*)&T[row * HF + c1] = make_float4(acc[i][4], acc[i][5], acc[i][6], acc[i][7]);
        }
    }
}

// ---------------- aggregation: O[v] = lrelu(sum_e w_e * T[src_e]) ----------------
// one wave per node, float2/lane = full 128-feat row, branchless clamped unroll-8

__global__ __launch_bounds__(256) void agg_k(const float* __restrict__ T, float* __restrict__ O,
                                             const int* __restrict__ rowptr,
                                             const int2* __restrict__ edg) {
    int v = blockIdx.x * 4 + (threadIdx.x >> 6);
    if (v >= N_NODES) return;
    int lane = threadIdx.x & 63;
    int f = lane * 2;
    int e0 = __builtin_amdgcn_readfirstlane(rowptr[v]);
    int e1 = __builtin_amdgcn_readfirstlane(rowptr[v + 1]);
    float ax = 0.f, ay = 0.f;
    for (int e = e0; e < e1; e += 8) {
        int   s[8];
        float w[8];
#pragma unroll
        for (int u = 0; u < 8; u++) {
            int idx = e + u;
            bool ok = idx < e1;
            int2 ed = edg[ok ? idx : e0];
            s[u] = ed.x;
            w[u] = ok ? __int_as_float(ed.y) : 0.f;
        }
        float2 hv[8];
#pragma unroll
        for (int u = 0; u < 8; u++)
            hv[u] = *(const float2*)&T[(size_t)s[u] * HF + f];
#pragma unroll
        for (int u = 0; u < 8; u++) {
            ax = fmaf(hv[u].x, w[u], ax);
            ay = fmaf(hv[u].y, w[u], ay);
        }
    }
    *(float2*)&O[(size_t)v * HF + f] = make_float2(lrelu(ax), lrelu(ay));
}

// ---------------- output layer: out = H @ Wfc + bfc (N=4) ----------------

__global__ void fc_k(const float* __restrict__ H, const float* __restrict__ W,
                     const float* __restrict__ b, float* __restrict__ out) {
    int r = blockIdx.x * 256 + threadIdx.x;
    if (r >= N_NODES) return;
    float4 acc = *(const float4*)b;
    const float4* h4 = (const float4*)(H + r * HF);
    const float4* w4 = (const float4*)W;
#pragma unroll
    for (int k4 = 0; k4 < 32; k4++) {
        float4 hv = h4[k4];
        float4 wa = w4[k4 * 4 + 0], wb = w4[k4 * 4 + 1];
        float4 wc = w4[k4 * 4 + 2], wd = w4[k4 * 4 + 3];
        acc.x = fmaf(hv.x, wa.x, acc.x); acc.y = fmaf(hv.x, wa.y, acc.y);
        acc.z = fmaf(hv.x, wa.z, acc.z); acc.w = fmaf(hv.x, wa.w, acc.w);
        acc.x = fmaf(hv.y, wb.x, acc.x); acc.y = fmaf(hv.y, wb.y, acc.y);
        acc.z = fmaf(hv.y, wb.z, acc.z); acc.w = fmaf(hv.y, wb.w, acc.w);
        acc.x = fmaf(hv.z, wc.x, acc.x); acc.y = fmaf(hv.z, wc.y, acc.y);
        acc.z = fmaf(hv.z, wc.z, acc.z); acc.w = fmaf(hv.z, wc.w, acc.w);
        acc.x = fmaf(hv.w, wd.x, acc.x); acc.y = fmaf(hv.w, wd.y, acc.y);
        acc.z = fmaf(hv.w, wd.z, acc.z); acc.w = fmaf(hv.w, wd.w, acc.w);
    }
    *(float4*)&out[r * NC] = acc;
}

// ---------------- driver ----------------

extern "C" void kernel_launch(void* const* d_in, const int* in_sizes, int n_in,
                              void* d_out, int out_size, void* d_ws, size_t ws_size,
                              hipStream_t stream) {
    const float* X   = (const float*)d_in[0];
    const int*   EI  = (const int*)d_in[1];
    const float* EA  = (const float*)d_in[2];
    const float* Win = (const float*)d_in[3];
    const float* bin = (const float*)d_in[4];
    const float* Wh  = (const float*)d_in[5];
    const float* bh  = (const float*)d_in[6];
    const float* Wfc = (const float*)d_in[7];
    const float* bfc = (const float*)d_in[8];
    float* out = (float*)d_out;
    const int* src = EI;
    const int* dst = EI + N_EDGES;

    char* ws = (char*)d_ws;
    size_t off = 0;
    float* A    = (float*)(ws + off); off += (size_t)N_NODES * HF * 4;
    float* B    = (float*)(ws + off); off += (size_t)N_NODES * HF * 4;
    int2* edg   = (int2*)(ws + off);  off += (size_t)N_EDGES * 8;
    int* rowptr = (int*)(ws + off);   off += (((size_t)(N_NODES + 1) * 4 + 15) / 16) * 16;
    int* cnt    = (int*)(ws + off);   off += (size_t)N_NODES * 4;
    int* fill   = (int*)(ws + off);   off += (size_t)N_NODES * 4;
    float* dinv = (float*)(ws + off); off += (size_t)N_NODES * 4;

    hipMemsetAsync(cnt, 0, N_NODES * 4, stream);
    hipMemsetAsync(fill, 0, N_NODES * 4, stream);
    count_deg_k<<<(N_EDGES + 255) / 256, 256, 0, stream>>>(dst, cnt);
    deginv_k<<<(N_NODES + 255) / 256, 256, 0, stream>>>(cnt, dinv);
    scan_k<<<1, 1024, 0, stream>>>(cnt, rowptr);
    fill_k<<<(N_EDGES + 255) / 256, 256, 0, stream>>>(src, dst, EA, rowptr, fill, edg, dinv);

    gemm_in_k<<<(N_NODES + 15) / 16, 256, 0, stream>>>(X, Win, bin, B);
    agg_k<<<(N_NODES + 3) / 4, 256, 0, stream>>>(B, A, rowptr, edg);
    for (int l = 0; l < NHL; l++) {
        gemm_h_k<<<(N_NODES + 127) / 128, 256, 0, stream>>>(
            A, Wh + (size_t)l * HF * HF, bh + (size_t)l * HF, B);
        agg_k<<<(N_NODES + 3) / 4, 256, 0, stream>>>(B, A, rowptr, edg);
    }
    fc_k<<<(N_NODES + 255) / 256, 256, 0, stream>>>(A, Wfc, bfc, out);
}